// Round 7
// baseline (127.686 us; speedup 1.0000x reference)
//
#include <hip/hip_runtime.h>

// RoundRobinGate: output = (0.0 scalar, one-hot [2,4096,16,512] f32, same tensor as
// bool->f32). Fully input-independent: 537 MB of zeros + 16,384 ones. Pure store-BW.
//
// Fill-shaped single kernel: 2048 persistent blocks x 256 threads, 64 grid-stride
// iterations, one lane-contiguous plain float4 store per iteration (1 KB per
// wave-instruction). NO nontemporal flag (R6 showed nt costs ~20% on gfx950).
// Branchless hot substitution: per iteration ~9 VALU (1 sub + 4 cmp/cndmask).
//
// Flat layout (float32), NTOT = 1 + 2*N1 = 134217729:
//   p = 0 -> scalar 0.0; p in [1,1+N1) -> one-hot (j=p-1); p in [1+N1,1+2N1) -> same.
// Span r (= p>>13, 16384 spans of 8192 floats): span-offset el corresponds to
// row r's j-offset el-1 (el>=1); el==0 is the previous row's offset-8191 element
// (never hot: hot <= 7935) or the p=0 scalar. Row hot offset hl = hot+1 where
// i = r & 4095, hot = ((i&15)<<9)|(i>>4).  r is uniform per block (t>>11, 256|2048).
// Tail float p = 134217728 (row 16383 offset 8191) is never hot -> 0.0 (thread 0).

typedef float floatx4 __attribute__((ext_vector_type(4)));

#define NTHR (2048u * 256u)     // grid threads; 33554432 quads / NTHR = 64 iterations

__global__ void __launch_bounds__(256) rr_gate_fill(floatx4* __restrict__ out4,
                                                    float* __restrict__ out) {
    const unsigned t   = blockIdx.x * 256u + threadIdx.x;
    const unsigned el0 = (t & 2047u) << 2;  // span-element idx of component 0 (invariant)
    unsigned r         = t >> 11;           // span id (uniform per block), +256/iter
    floatx4* p         = out4 + t;

#pragma unroll 8
    for (unsigned it = 0; it < 64u; ++it) {
        const unsigned i  = r & 4095u;                          // token row   (SALU)
        const unsigned hl = (((i & 15u) << 9) | (i >> 4)) + 1u; // hot span-off (SALU)
        const unsigned d  = hl - el0;                           // per-thread
        floatx4 v;
        v.x = (d == 0u) ? 1.0f : 0.0f;
        v.y = (d == 1u) ? 1.0f : 0.0f;
        v.z = (d == 2u) ? 1.0f : 0.0f;
        v.w = (d == 3u) ? 1.0f : 0.0f;
        *p = v;
        p += NTHR;
        r += 256u;
    }
    // Final odd element (index 134217728): always 0.
    if (t == 0) {
        out[134217728u] = 0.0f;
    }
}

extern "C" void kernel_launch(void* const* d_in, const int* in_sizes, int n_in,
                              void* d_out, int out_size, void* d_ws, size_t ws_size,
                              hipStream_t stream) {
    (void)d_in; (void)in_sizes; (void)n_in; (void)d_ws; (void)ws_size; (void)out_size;
    hipLaunchKernelGGL(rr_gate_fill, dim3(2048), dim3(256), 0, stream,
                       (floatx4*)d_out, (float*)d_out);
}